// Round 9
// baseline (260.606 us; speedup 1.0000x reference)
//
#include <hip/hip_runtime.h>
#include <hip/hip_bf16.h>

// B=8, N=2048, DX=1024, DK=DV=128. Inputs fp32, output fp32.
// out = softmax(K V^T / sqrt(128)) V, K = x Wk^T + bk, V = x Wv^T + bv.
// R9: drain-free pipelines. flash: no barriers, V/VT fragments direct
// global->VGPR, XCD batch swizzle. kv_gemm: B-frags direct global->VGPR,
// sA-only LDS with lgkm-only asm barrier (vmcnt stays in flight).

typedef short s16x8 __attribute__((ext_vector_type(8)));
typedef float f32x4 __attribute__((ext_vector_type(4)));
typedef unsigned short u16;

__device__ __forceinline__ float bf2f(u16 u) {
  unsigned int v = ((unsigned int)u) << 16;
  return __builtin_bit_cast(float, v);
}
__device__ __forceinline__ u16 f2bf(float f) {
  unsigned int u = __builtin_bit_cast(unsigned int, f);
  u += 0x7fffu + ((u >> 16) & 1u);   // RNE
  return (u16)(u >> 16);
}
__device__ __forceinline__ unsigned pack_bf2(float a, float b) {
  unsigned ua = __builtin_bit_cast(unsigned, a) + 0x8000u;
  unsigned ub = __builtin_bit_cast(unsigned, b) + 0x8000u;
  return __builtin_amdgcn_perm(ub, ua, 0x07060302u);
}
// barrier that waits only LDS ops: prefetched global loads stay in flight
__device__ __forceinline__ void lgkm_barrier() {
  asm volatile("s_waitcnt lgkmcnt(0)\n\ts_barrier" ::: "memory");
}

// ---------------- Kernel W: weights fp32 -> bf16 (wk||wv -> wbf[256][1024]) --
__global__ __launch_bounds__(256, 4) void wconv_kernel(
    const float* __restrict__ wk, const float* __restrict__ wv,
    u16* __restrict__ wbf)
{
  const int e = (blockIdx.x * 256 + threadIdx.x) * 8;
  const float* src = (e < 131072) ? (wk + e) : (wv + (e - 131072));
  float4 a = *(const float4*)src;
  float4 b = *(const float4*)(src + 4);
  union { unsigned u[4]; s16x8 v; } pk;
  pk.u[0] = pack_bf2(a.x, a.y); pk.u[1] = pack_bf2(a.z, a.w);
  pk.u[2] = pack_bf2(b.x, b.y); pk.u[3] = pack_bf2(b.z, b.w);
  *(s16x8*)(wbf + e) = pk.v;
}

// ---------------- Kernel A: fused K|V projection GEMM (+ V^T emit) -----------
// grid 512: block = 32 rows x 256 cols, BK=64, 16 steps. Wave w: cols w*64.
// A via tiny dbuf LDS (lgkm barrier only); B-frags global->reg, 1-step ahead.
__global__ __launch_bounds__(256, 2) void kv_gemm_kernel(
    const float* __restrict__ x, const u16* __restrict__ wbf,
    const float* __restrict__ bk, const float* __restrict__ bv,
    u16* __restrict__ Kout, u16* __restrict__ Vout, u16* __restrict__ VTout)
{
  __shared__ u16 sA[2][4 * 512];    // [buf][slice=rb*2+ks][lane][8] = 4 KB each

  const int tid  = threadIdx.x;
  const int wave = tid >> 6;
  const int lane = tid & 63;
  const int l16  = lane & 15;
  const int lq   = lane >> 4;
  const int row0 = blockIdx.x * 32;

  f32x4 acc[2][4];
  for (int i = 0; i < 2; ++i)
    for (int j = 0; j < 4; ++j) acc[i][j] = (f32x4){0.f, 0.f, 0.f, 0.f};

  // A staging: thread -> (row = tid>>3, kchunk = tid&7); slot in frag order
  const int kc = tid & 7, arow = tid >> 3;
  const float* aSrc = x + (size_t)(row0 + arow) * 1024 + kc * 8;
  const int aSlot = ((((arow >> 4) * 2 + (kc >> 2)) * 64) + (kc & 3) * 16 + (arow & 15)) * 8;

  // B frags: frag f=(cb,ks): col = wave*64 + cb*16 + l16, k = s*64 + ks*32 + lq*8
  const u16* bBase = wbf + (size_t)(wave * 64 + l16) * 1024 + lq * 8;
  s16x8 bcur[8], bnxt[8];

  // prologue: pack A(0); load A(1); load B(0)
  {
    float4 a0 = *(const float4*)aSrc;
    float4 a1 = *(const float4*)(aSrc + 4);
    union { unsigned u[4]; s16x8 v; } pk;
    pk.u[0] = pack_bf2(a0.x, a0.y); pk.u[1] = pack_bf2(a0.z, a0.w);
    pk.u[2] = pack_bf2(a1.x, a1.y); pk.u[3] = pack_bf2(a1.z, a1.w);
    *(s16x8*)(&sA[0][aSlot]) = pk.v;
  }
  float4 p0a = *(const float4*)(aSrc + 64);
  float4 p0b = *(const float4*)(aSrc + 68);
  float4 p1a, p1b;
#pragma unroll
  for (int f = 0; f < 8; ++f)
    bcur[f] = *(const s16x8*)(bBase + (f >> 1) * 16384 + (f & 1) * 32);
  lgkm_barrier();

  for (int s = 0; s < 16; ++s) {
    const int buf = s & 1;
    // A-frags for this step
    s16x8 af[2][2];
#pragma unroll
    for (int rb = 0; rb < 2; ++rb)
#pragma unroll
      for (int ks = 0; ks < 2; ++ks)
        af[rb][ks] = *(const s16x8*)(&sA[buf][((rb * 2 + ks) * 64 + lane) * 8]);
    // prefetch B(s+1), A(s+2)
    if (s + 1 < 16) {
      const int koff = (s + 1) * 64;
#pragma unroll
      for (int f = 0; f < 8; ++f)
        bnxt[f] = *(const s16x8*)(bBase + (f >> 1) * 16384 + (f & 1) * 32 + koff);
    }
    if (s + 2 < 16) {
      p1a = *(const float4*)(aSrc + (s + 2) * 64);
      p1b = *(const float4*)(aSrc + (s + 2) * 64 + 4);
    }
    // MFMAs
#pragma unroll
    for (int rb = 0; rb < 2; ++rb)
#pragma unroll
      for (int cb = 0; cb < 4; ++cb)
#pragma unroll
        for (int ks = 0; ks < 2; ++ks)
          acc[rb][cb] = __builtin_amdgcn_mfma_f32_16x16x32_bf16(
              af[rb][ks], bcur[cb * 2 + ks], acc[rb][cb], 0, 0, 0);
    // pack A(s+1) into the other buffer
    if (s + 1 < 16) {
      union { unsigned u[4]; s16x8 v; } pk;
      pk.u[0] = pack_bf2(p0a.x, p0a.y); pk.u[1] = pack_bf2(p0a.z, p0a.w);
      pk.u[2] = pack_bf2(p0b.x, p0b.y); pk.u[3] = pack_bf2(p0b.z, p0b.w);
      *(s16x8*)(&sA[buf ^ 1][aSlot]) = pk.v;
      p0a = p1a; p0b = p1b;
#pragma unroll
      for (int f = 0; f < 8; ++f) bcur[f] = bnxt[f];
    }
    lgkm_barrier();   // LDS-only drain; global prefetches remain in flight
  }

  const int  colBase = wave * 64;
  const bool isV = (wave >= 2);
  u16* outN = isV ? Vout : Kout;
  float fbias[4];
  for (int cb = 0; cb < 4; ++cb) {
    const int col = colBase + cb * 16 + l16;
    fbias[cb] = isV ? bv[col - 128] : bk[col];
  }
  for (int rb = 0; rb < 2; ++rb) {
    const int grow0 = row0 + rb * 16 + lq * 4;
    for (int cb = 0; cb < 4; ++cb) {
      const int gcol = colBase + cb * 16 + l16;
      const int ocol = isV ? (gcol - 128) : gcol;
      union { u16 u[4]; unsigned long long ull; } pk;
      for (int r = 0; r < 4; ++r) {
        u16 h = f2bf(acc[rb][cb][r] + fbias[cb]);
        outN[(size_t)(grow0 + r) * 128 + ocol] = h;
        pk.u[r] = h;
      }
      if (isV) {
        const int bidx = grow0 >> 11;
        const int n    = grow0 & 2047;
        *(unsigned long long*)(VTout + (size_t)bidx * 128 * 2048 + (size_t)ocol * 2048 + n) = pk.ull;
      }
    }
  }
}

// ---------------- Kernel B: flash attention, barrier-free ---------------------
// flat grid 512: b = idx&7 (XCD swizzle), qt = (idx>>3)&31, z = idx>>8.
// 64 q-rows/block, m-tiles of 64, no-max softmax, all operands via registers.
__global__ __launch_bounds__(256, 2) void flash_kernel(
    const u16* __restrict__ Kmat, const u16* __restrict__ Vmat,
    const u16* __restrict__ VT, float* __restrict__ out,
    float* __restrict__ Opart, float* __restrict__ lbuf)
{
  __shared__ u16 sP[64 * 66];        // wave-private rows; stride 66

  const int tid  = threadIdx.x;
  const int wave = tid >> 6;
  const int lane = tid & 63;
  const int l16  = lane & 15;
  const int lq   = lane >> 4;
  const int b    = blockIdx.x & 7;
  const int q0   = ((blockIdx.x >> 3) & 31) * 64;
  const int z    = blockIdx.x >> 8;
  const int mstart = z * 1024;       // z in {0,1}
  const float scale = 0.08838834764831845f;   // 1/sqrt(128)

  // K fragments (A-operand, wave-private) in registers
  s16x8 kf[4];
  {
    const u16* Kb = Kmat + ((size_t)b * 2048 + q0 + wave * 16 + l16) * 128 + lq * 8;
#pragma unroll
    for (int ks = 0; ks < 4; ++ks) kf[ks] = *(const s16x8*)(Kb + ks * 32);
  }
  const u16* vrow  = Vmat + (size_t)b * 2048 * 128 + l16 * 128 + lq * 8;
  const u16* vtrow = VT   + (size_t)b * 128 * 2048 + l16 * 2048 + lq * 8;

  f32x4 oacc[8];
  for (int v = 0; v < 8; ++v) oacc[v] = (f32x4){0.f, 0.f, 0.f, 0.f};
  float lrow[4] = {0.f, 0.f, 0.f, 0.f};

#pragma unroll 2
  for (int mt = 0; mt < 16; ++mt) {
    const int m0 = mstart + mt * 64;

    // S = K.V^T : B-frags straight from global (16 x dwordx4 in flight)
    s16x8 vf[16];
#pragma unroll
    for (int t = 0; t < 4; ++t)
#pragma unroll
      for (int ks = 0; ks < 4; ++ks)
        vf[t * 4 + ks] = *(const s16x8*)(vrow + (size_t)(m0 + t * 16) * 128 + ks * 32);
    f32x4 sacc[4];
    for (int t = 0; t < 4; ++t) sacc[t] = (f32x4){0.f, 0.f, 0.f, 0.f};
#pragma unroll
    for (int ks = 0; ks < 4; ++ks)
#pragma unroll
      for (int t = 0; t < 4; ++t)
        sacc[t] = __builtin_amdgcn_mfma_f32_16x16x32_bf16(kf[ks], vf[t * 4 + ks], sacc[t], 0, 0, 0);

    // PV B-frags (V^T) issued early; latency covered by softmax below
    s16x8 vtf[16];
#pragma unroll
    for (int vt = 0; vt < 8; ++vt)
#pragma unroll
      for (int ksm = 0; ksm < 2; ++ksm)
        vtf[vt * 2 + ksm] = *(const s16x8*)(vtrow + (size_t)vt * 32768 + m0 + ksm * 32);

    // softmax without max-shift (logits bounded); p = exp(s*scale)
#pragma unroll
    for (int r = 0; r < 4; ++r) {
      const int prow = (wave * 16 + lq * 4 + r) * 66;
      float rs = 0.f;
#pragma unroll
      for (int t = 0; t < 4; ++t) {
        float p = __expf(sacc[t][r] * scale);
        u16 h = f2bf(p);
        sP[prow + t * 16 + l16] = h;
        rs += bf2f(h);
      }
      lrow[r] += rs;
    }

    // O += P.V  (sP wave-private; lgkm deps handled by compiler)
#pragma unroll
    for (int ksm = 0; ksm < 2; ++ksm) {
      s16x8 a = *(const s16x8*)(&sP[(wave * 16 + l16) * 66 + ksm * 32 + lq * 8]);
#pragma unroll
      for (int vt = 0; vt < 8; ++vt)
        oacc[vt] = __builtin_amdgcn_mfma_f32_16x16x32_bf16(a, vtf[vt * 2 + ksm], oacc[vt], 0, 0, 0);
    }
  }

  for (int r = 0; r < 4; ++r) {
    lrow[r] += __shfl_xor(lrow[r], 1);
    lrow[r] += __shfl_xor(lrow[r], 2);
    lrow[r] += __shfl_xor(lrow[r], 4);
    lrow[r] += __shfl_xor(lrow[r], 8);
  }

  const size_t rowg = (size_t)b * 2048 + q0 + wave * 16;
  float* Op = Opart + (size_t)z * 2097152;
  float* lp = lbuf + (size_t)z * 32768;
  for (int r = 0; r < 4; ++r)
    for (int v = 0; v < 8; ++v)
      Op[(rowg + lq * 4 + r) * 128 + v * 16 + l16] = oacc[v][r];
  if (l16 == 0)
    for (int r = 0; r < 4; ++r)
      lp[rowg + lq * 4 + r] = lrow[r];
}

// ---------------- Kernel C: combine 2 KV-split partials ----------------------
__global__ __launch_bounds__(256, 4) void combine_kernel(
    const float* __restrict__ Opart, const float* __restrict__ lbuf,
    float* __restrict__ out)
{
  const int idx = blockIdx.x * 256 + threadIdx.x;    // float4 idx, 524288 total
  const int row = idx >> 5;
  const float4 o0 = ((const float4*)Opart)[idx];
  const float4 o1 = ((const float4*)(Opart + 2097152))[idx];
  const float inv = 1.f / (lbuf[row] + lbuf[32768 + row]);
  float4 o;
  o.x = (o0.x + o1.x) * inv;
  o.y = (o0.y + o1.y) * inv;
  o.z = (o0.z + o1.z) * inv;
  o.w = (o0.w + o1.w) * inv;
  ((float4*)out)[idx] = o;
}

extern "C" void kernel_launch(void* const* d_in, const int* in_sizes, int n_in,
                              void* d_out, int out_size, void* d_ws, size_t ws_size,
                              hipStream_t stream) {
  const float* x  = (const float*)d_in[0];
  const float* wk = (const float*)d_in[3];
  const float* bk = (const float*)d_in[4];
  const float* wv = (const float*)d_in[5];
  const float* bv = (const float*)d_in[6];

  u16* ws   = (u16*)d_ws;
  u16* wbf  = ws;                             // 512 KB
  u16* Kmat = ws + 262144;                    // 4 MB
  u16* Vmat = Kmat + (size_t)16384 * 128;     // 4 MB
  u16* VTm  = Vmat + (size_t)16384 * 128;     // 4 MB
  float* Opart = (float*)(VTm + (size_t)16384 * 128);  // 2 x 8 MB
  float* lbuf  = Opart + 2 * 2097152;                  // 2 x 128 KB

  wconv_kernel<<<128, 256, 0, stream>>>(wk, wv, wbf);
  kv_gemm_kernel<<<512, 256, 0, stream>>>(x, wbf, bk, bv, Kmat, Vmat, VTm);
  flash_kernel<<<512, 256, 0, stream>>>(Kmat, Vmat, VTm, (float*)d_out, Opart, lbuf);
  combine_kernel<<<2048, 256, 0, stream>>>(Opart, lbuf, (float*)d_out);
}